// Round 9
// baseline (502.387 us; speedup 1.0000x reference)
//
#include <hip/hip_runtime.h>
#include <hip/hip_fp16.h>

#define N_NODES 50000
#define N_EDGES 400000
#define N_GRAPHS 64
#define HID 200
#define NUM_OUT 16
#define NLAYERS 5
#define CPAD 256            // padded channel count (K and N of GEMMs)
#define MPAD 50048          // padded row count (multiple of 64)
#define SCAN_B 196          // ceil(N_NODES/256)
#define EROWS 32            // rows per embed block

typedef unsigned short ushort_t;
typedef unsigned int uint_t;
typedef _Float16 half8 __attribute__((ext_vector_type(8)));
typedef float f32x4 __attribute__((ext_vector_type(4)));

__device__ __forceinline__ ushort_t f2h(float f) {
  return __half_as_ushort(__float2half(f));
}

// packed fp16 helpers
__device__ __forceinline__ uint_t pk_add(uint_t a, uint_t b) {
  uint_t d; asm("v_pk_add_f16 %0, %1, %2" : "=v"(d) : "v"(a), "v"(b)); return d;
}
__device__ __forceinline__ uint_t pk_relu(uint_t a) {
  uint_t d; asm("v_pk_max_f16 %0, %1, 0" : "=v"(d) : "v"(a)); return d;
}

__device__ __forceinline__ void gload_lds16(const void* g, void* l) {
  __builtin_amdgcn_global_load_lds(
      (const __attribute__((address_space(1))) unsigned int*)g,
      (__attribute__((address_space(3))) unsigned int*)l, 16, 0, 0);
}

// ---------------------------------------------------------------------------
// embed + pool0 fused: 32 rows per block, thread = column (fp16 x out).
__global__ __launch_bounds__(256) void embed_pool(
    const int* __restrict__ kind, const int* __restrict__ content,
    const float* __restrict__ kind_emb, const float* __restrict__ inst2vec,
    const float* __restrict__ type_emb, const int* __restrict__ bv,
    ushort_t* __restrict__ x, float* __restrict__ pool0) {
  __shared__ int k_s[EROWS], c_s[EROWS], g_s[EROWS];
  int t = threadIdx.x;
  size_t r0 = (size_t)blockIdx.x * EROWS;
  if (t < EROWS) {
    size_t r = r0 + t;
    int k = 0, cn = 0, g = -1;
    if (r < N_NODES) { k = kind[r]; cn = content[r]; g = bv[r]; }
    k_s[t] = k; c_s[t] = cn; g_s[t] = g;
  }
  __syncthreads();
  int c = t;
  float pacc = 0.f; int gcur = -1;
  #pragma unroll 2
  for (int rr = 0; rr < EROWS; ++rr) {
    size_t r = r0 + rr;
    if (r < N_NODES) {
      float f = 0.f;
      if (c < HID) {
        int k = k_s[rr];
        f = kind_emb[k * HID + c] +
            ((k == 0) ? inst2vec[(size_t)c_s[rr] * HID + c] : type_emb[c]);
      }
      x[r * CPAD + c] = f2h(f);
      int g = g_s[rr];
      if (g != gcur) {
        if (gcur >= 0 && c < HID) atomicAdd(&pool0[gcur * HID + c], pacc);
        pacc = 0.f; gcur = g;
      }
      pacc += f;
    } else {
      x[r * CPAD + c] = 0;
    }
  }
  if (gcur >= 0 && c < HID) atomicAdd(&pool0[gcur * HID + c], pacc);
}

// edge-embedding table, packed fp16: ecomb[61][128] uints (=256 half channels).
// Row 60 = -65504 sentinel (dummy edges; relu clamps to 0).
__global__ void ecomb_kernel(const float* __restrict__ etype_emb, const float* __restrict__ epos_emb,
                             uint_t* __restrict__ ecomb) {
  int code = blockIdx.x; int cp = threadIdx.x;   // cp in [0,128)
  if (cp >= 128) return;
  uint_t v;
  if (code == 60) {
    v = 0xFBFFFBFFu;   // half -65504 in both halves
  } else {
    int c0 = cp * 2, c1 = cp * 2 + 1;
    float f0 = (c0 < HID) ? etype_emb[(code / 20) * HID + c0] + epos_emb[(code % 20) * HID + c0] : 0.f;
    float f1 = (c1 < HID) ? etype_emb[(code / 20) * HID + c1] + epos_emb[(code % 20) * HID + c1] : 0.f;
    v = (uint_t)f2h(f0) | ((uint_t)f2h(f1) << 16);
  }
  ecomb[code * 128 + cp] = v;
}

// weights: fp16, transposed, padded.  Wt[g][n][k], g=2i -> W1[i], g=2i+1 -> W2[i]
__global__ void prep_w(const float* __restrict__ W1, const float* __restrict__ W2,
                       ushort_t* __restrict__ Wt) {
  int idx = blockIdx.x * 256 + threadIdx.x;   // 10*256*256 total
  int g = idx >> 16; int rem = idx & 65535; int n = rem >> 8; int k = rem & 255;
  float v = 0.f;
  if (n < HID && k < HID) {
    int i = g >> 1;
    v = (g & 1) ? W2[(size_t)i * HID * HID + (size_t)k * HID + n]
                : W1[(size_t)i * HID * HID + (size_t)k * HID + n];
  }
  Wt[idx] = f2h(v);
}

// epilogue tables: out = relu(acc*s + t); pad channels s=t=0 (keeps pads zero)
__global__ void prep_st(const float* __restrict__ b1, const float* __restrict__ bn_g,
                        const float* __restrict__ bn_b, const float* __restrict__ bn_m,
                        const float* __restrict__ bn_v, const float* __restrict__ b2,
                        float2* __restrict__ ST) {
  int idx = blockIdx.x * 256 + threadIdx.x;   // 10*256
  int g = idx >> 8, c = idx & 255;
  float s = 0.f, t = 0.f;
  if (c < HID) {
    int i = g >> 1;
    if (g & 1) { s = 1.f; t = b2[i * HID + c]; }
    else {
      float sc = bn_g[i * HID + c] * rsqrtf(bn_v[i * HID + c] + 1e-5f);
      s = sc; t = (b1[i * HID + c] - bn_m[i * HID + c]) * sc + bn_b[i * HID + c];
    }
  }
  ST[idx] = make_float2(s, t);
}

// CSR build (padded degrees: multiple of 4)
__global__ void hist_kernel(const int* __restrict__ dst, int* __restrict__ deg) {
  int e = blockIdx.x * 256 + threadIdx.x;
  if (e < N_EDGES) atomicAdd(&deg[dst[e]], 1);
}

__global__ void scan1_kernel(const int* __restrict__ deg, int* __restrict__ bsum) {
  __shared__ int red[256];
  int b = blockIdx.x, t = threadIdx.x;
  int i = b * 256 + t;
  red[t] = (i < N_NODES) ? ((deg[i] + 3) & ~3) : 0;
  __syncthreads();
  for (int off = 128; off > 0; off >>= 1) {
    if (t < off) red[t] += red[t + off];
    __syncthreads();
  }
  if (t == 0) bsum[b] = red[0];
}

__global__ void scan2_kernel(const int* __restrict__ bsum, int* __restrict__ bpre,
                             int* __restrict__ offs, const int* __restrict__ bv,
                             int* __restrict__ gstart) {
  __shared__ int buf[256];
  int t = threadIdx.x;
  if (t <= N_GRAPHS) {
    if (t == N_GRAPHS) gstart[N_GRAPHS] = N_NODES;
    else {
      int lo = 0, hi = N_NODES;
      while (lo < hi) { int mid = (lo + hi) >> 1; if (bv[mid] < t) lo = mid + 1; else hi = mid; }
      gstart[t] = lo;
    }
  }
  int v = (t < SCAN_B) ? bsum[t] : 0;
  buf[t] = v;
  __syncthreads();
  for (int off = 1; off < 256; off <<= 1) {
    int tv = (t >= off) ? buf[t - off] : 0;
    __syncthreads();
    buf[t] += tv;
    __syncthreads();
  }
  if (t < SCAN_B) bpre[t] = buf[t] - v;
  if (t == 255) offs[N_NODES] = buf[255];
}

__global__ void scan3_kernel(const int* __restrict__ deg, const int* __restrict__ bpre,
                             int* __restrict__ offs, int* __restrict__ cursor) {
  __shared__ int buf[256];
  int b = blockIdx.x, t = threadIdx.x;
  int i = b * 256 + t;
  int v = (i < N_NODES) ? ((deg[i] + 3) & ~3) : 0;
  buf[t] = v;
  __syncthreads();
  for (int off = 1; off < 256; off <<= 1) {
    int tv = (t >= off) ? buf[t - off] : 0;
    __syncthreads();
    buf[t] += tv;
    __syncthreads();
  }
  if (i < N_NODES) {
    int e = bpre[b] + buf[t] - v;
    offs[i] = e; cursor[i] = e;
  }
}

// scatter real edges: pack (src,code) into one int
__global__ void scatter_kernel(const int* __restrict__ src, const int* __restrict__ dst,
                               const int* __restrict__ etype, const int* __restrict__ epos,
                               int* __restrict__ cursor, int* __restrict__ e_pack) {
  int e = blockIdx.x * 256 + threadIdx.x;
  if (e >= N_EDGES) return;
  int d = dst[e];
  int slot = atomicAdd(&cursor[d], 1);
  int p = epos[e]; if (p > 19) p = 19;
  e_pack[slot] = (src[e] << 6) | (etype[e] * 20 + p);
}

// fill padding slots + a 4-int sentinel chunk past the CSR end.
// Dummy edge = (src 0 | code 60): gathers the L1-hot node-0 row; the -65504
// ecomb sentinel relu's the contribution to zero.
__global__ void fill_kernel(const int* __restrict__ cursor, const int* __restrict__ offs,
                            int* __restrict__ e_pack) {
  int n = blockIdx.x * 256 + threadIdx.x;
  if (n == 0) {
    int total = offs[N_NODES];
    e_pack[total + 0] = 60; e_pack[total + 1] = 60;
    e_pack[total + 2] = 60; e_pack[total + 3] = 60;
  }
  if (n >= N_NODES) return;
  int e = offs[n + 1];
  for (int j = cursor[n]; j < e; ++j) e_pack[j] = 60;   // (0<<6)|60
}

// GINE aggregation (fp16 packed math): one wave per 4 nodes (4 interleaved
// edge streams, 4-edge chunks -> 16 x-gathers in flight). Uniform rounds loop:
// exhausted streams read the sentinel chunk (L1-hot, contributes 0).
__global__ __launch_bounds__(256) void agg_kernel(
    const ushort_t* __restrict__ x, ushort_t* __restrict__ y,
    const int* __restrict__ offs, const int* __restrict__ e_pack,
    const uint_t* __restrict__ ecomb) {
  int wid = threadIdx.x >> 6, lane = threadIdx.x & 63;
  int n0 = (blockIdx.x * 4 + wid) * 4;
  if (n0 >= N_NODES) return;
  const uint2* xv = (const uint2*)x;     // 4 fp16 ch per lane
  const uint2* ecv = (const uint2*)ecomb;
  uint2* yv = (uint2*)y;
  if (lane >= 50) {
    #pragma unroll
    for (int q = 0; q < 4; ++q)
      yv[(size_t)(n0 + q) * 64 + lane] = make_uint2(0u, 0u);
    return;
  }
  int o0 = offs[n0], o1 = offs[n0 + 1], o2 = offs[n0 + 2];
  int o3 = offs[n0 + 3], o4 = offs[n0 + 4];
  int sent = offs[N_NODES];
  int j0 = o0, e0 = o1, j1 = o1, e1 = o2, j2 = o2, e2 = o3, j3 = o3, e3 = o4;
  int rounds = max(max(e0 - j0, e1 - j1), max(e2 - j2, e3 - j3)) >> 2;
  uint_t accl[4] = {0u, 0u, 0u, 0u}, acch[4] = {0u, 0u, 0u, 0u};
  const int4* ep4 = (const int4*)e_pack;

  for (int t = 0; t < rounds; ++t) {
    int i0 = (j0 < e0) ? j0 : sent; j0 += 4;
    int i1 = (j1 < e1) ? j1 : sent; j1 += 4;
    int i2 = (j2 < e2) ? j2 : sent; j2 += 4;
    int i3 = (j3 < e3) ? j3 : sent; j3 += 4;
    int4 p[4];
    p[0] = ep4[i0 >> 2]; p[1] = ep4[i1 >> 2];
    p[2] = ep4[i2 >> 2]; p[3] = ep4[i3 >> 2];
    uint2 xr[4][4], er[4][4];
    #pragma unroll
    for (int q = 0; q < 4; ++q) {
      xr[q][0] = xv[(size_t)(p[q].x >> 6) * 64 + lane];
      xr[q][1] = xv[(size_t)(p[q].y >> 6) * 64 + lane];
      xr[q][2] = xv[(size_t)(p[q].z >> 6) * 64 + lane];
      xr[q][3] = xv[(size_t)(p[q].w >> 6) * 64 + lane];
    }
    #pragma unroll
    for (int q = 0; q < 4; ++q) {
      er[q][0] = ecv[(size_t)(p[q].x & 63) * 64 + lane];
      er[q][1] = ecv[(size_t)(p[q].y & 63) * 64 + lane];
      er[q][2] = ecv[(size_t)(p[q].z & 63) * 64 + lane];
      er[q][3] = ecv[(size_t)(p[q].w & 63) * 64 + lane];
    }
    #pragma unroll
    for (int q = 0; q < 4; ++q) {
      #pragma unroll
      for (int u = 0; u < 4; ++u) {
        accl[q] = pk_add(accl[q], pk_relu(pk_add(xr[q][u].x, er[q][u].x)));
        acch[q] = pk_add(acch[q], pk_relu(pk_add(xr[q][u].y, er[q][u].y)));
      }
    }
  }
  #pragma unroll
  for (int q = 0; q < 4; ++q) {
    uint2 xn = xv[(size_t)(n0 + q) * 64 + lane];
    uint2 o;
    o.x = pk_add(xn.x, accl[q]);
    o.y = pk_add(xn.y, acch[q]);
    yv[(size_t)(n0 + q) * 64 + lane] = o;
  }
}

// ---------------------------------------------------------------------------
// Fused layer (fp16): X = relu(relu(BN(Y@W1)) @ W2 + b2) + per-graph pooling.
// 2-phase counted-vmcnt pipeline: A tile double-buffered; stage-W-then-
// prefetch-A order so vmcnt(2) leaves the next A tile in flight.
__global__ __launch_bounds__(256, 2) void fused_layer(
    const ushort_t* __restrict__ Y, ushort_t* __restrict__ X,
    const ushort_t* __restrict__ W1t, const ushort_t* __restrict__ W2t,
    const float2* __restrict__ ST1, const float2* __restrict__ ST2,
    const int* __restrict__ bv, const int* __restrict__ gstart,
    float* __restrict__ pools_out) {
  __shared__ char lds[80 * 1024];
  char* A_l0 = lds;             //  8KB: 64 rows x 128B (A k-tile, buf 0)
  char* A_l1 = lds + 8192;      //  8KB: buf 1
  char* W_l  = lds + 16384;     // 32KB: 256 rows x 128B (W1/W2 k-tile)
  char* T_l  = lds + 49152;     // 32KB: 64 rows x 512B (intermediate, swizzled)
  const int tid = threadIdx.x;
  const int lane = tid & 63, wn = tid >> 6;
  const size_t r0 = (size_t)blockIdx.x * 64;
  const char* Ab = (const char*)Y;
  const char* W1c = (const char*)W1t;
  const char* W2c = (const char*)W2t;

  f32x4 acc[4][4];
  #pragma unroll
  for (int mi = 0; mi < 4; mi++)
    #pragma unroll
    for (int ni = 0; ni < 4; ni++) acc[mi][ni] = (f32x4){0.f, 0.f, 0.f, 0.f};

  // ---- phase A: acc = Y_tile @ W1, pipelined ----
  {
    #pragma unroll
    for (int c = 0; c < 2; c++) {
      int d = tid * 16 + c * 4096;
      int rowd = d >> 7, slot = (d >> 4) & 7, lslot = slot ^ (rowd & 7);
      gload_lds16(Ab + (r0 + rowd) * 512 + 0 + lslot * 16, A_l0 + d);
    }
    #pragma unroll
    for (int t = 0; t < 4; ++t) {
      const int k0 = t * 64;
      #pragma unroll
      for (int c = 0; c < 8; c++) {
        int d = tid * 16 + c * 4096;
        int rowd = d >> 7, slot = (d >> 4) & 7, lslot = slot ^ (rowd & 7);
        gload_lds16(W1c + (size_t)rowd * 512 + k0 * 2 + lslot * 16, W_l + d);
      }
      if (t < 3) {
        char* nbuf = (t & 1) ? A_l0 : A_l1;
        #pragma unroll
        for (int c = 0; c < 2; c++) {
          int d = tid * 16 + c * 4096;
          int rowd = d >> 7, slot = (d >> 4) & 7, lslot = slot ^ (rowd & 7);
          gload_lds16(Ab + (r0 + rowd) * 512 + (k0 + 64) * 2 + lslot * 16, nbuf + d);
        }
        asm volatile("s_waitcnt vmcnt(2)" ::: "memory");
      } else {
        asm volatile("s_waitcnt vmcnt(0)" ::: "memory");
      }
      __builtin_amdgcn_sched_barrier(0);
      __builtin_amdgcn_s_barrier();
      const char* Abuf = (t & 1) ? A_l1 : A_l0;
      #pragma unroll
      for (int s = 0; s < 2; s++) {
        half8 bfr[4];
        #pragma unroll
        for (int ni = 0; ni < 4; ni++) {
          int brow = wn * 64 + ni * 16 + (lane & 15);
          int off = brow * 128 + (((s * 4 + (lane >> 4)) ^ (brow & 7)) << 4);
          bfr[ni] = *(const half8*)(W_l + off);
        }
        #pragma unroll
        for (int mi = 0; mi < 4; mi++) {
          int arow = mi * 16 + (lane & 15);
          int off = arow * 128 + (((s * 4 + (lane >> 4)) ^ (arow & 7)) << 4);
          half8 af = *(const half8*)(Abuf + off);
          #pragma unroll
          for (int ni = 0; ni < 4; ni++)
            acc[mi][ni] = __builtin_amdgcn_mfma_f32_16x16x32_f16(af, bfr[ni], acc[mi][ni], 0, 0, 0);
        }
      }
      __builtin_amdgcn_s_barrier();
    }
  }

  // ---- T = relu(BN(acc)) -> LDS (fp16, swizzled rows of 512B) ----
  #pragma unroll
  for (int ni = 0; ni < 4; ni++) {
    int col = wn * 64 + ni * 16 + (lane & 15);
    float2 st = ST1[col];
    #pragma unroll
    for (int mi = 0; mi < 4; mi++) {
      int rbase = mi * 16 + (lane >> 4) * 4;
      #pragma unroll
      for (int j = 0; j < 4; j++) {
        int row = rbase + j;
        float v = fmaxf(fmaf(acc[mi][ni][j], st.x, st.y), 0.f);
        int boff = row * 512 + ((((col >> 3) ^ (row & 7)) << 4) | ((col & 7) * 2));
        *(ushort_t*)(T_l + boff) = f2h(v);
      }
    }
  }
  #pragma unroll
  for (int mi = 0; mi < 4; mi++)
    #pragma unroll
    for (int ni = 0; ni < 4; ni++) acc[mi][ni] = (f32x4){0.f, 0.f, 0.f, 0.f};
  __syncthreads();

  // ---- phase B: acc = T @ W2 (W2 L2-hot; simple stage/drain per k-tile) ----
  #pragma unroll
  for (int t = 0; t < 4; ++t) {
    const int k0 = t * 64;
    #pragma unroll
    for (int c = 0; c < 8; c++) {
      int d = tid * 16 + c * 4096;
      int rowd = d >> 7, slot = (d >> 4) & 7, lslot = slot ^ (rowd & 7);
      gload_lds16(W2c + (size_t)rowd * 512 + k0 * 2 + lslot * 16, W_l + d);
    }
    asm volatile("s_waitcnt vmcnt(0)" ::: "memory");
    __builtin_amdgcn_sched_barrier(0);
    __builtin_amdgcn_s_barrier();
    #pragma unroll
    for (int s = 0; s < 2; s++) {
      half8 bfr[4];
      #pragma unroll
      for (int ni = 0; ni < 4; ni++) {
        int brow = wn * 64 + ni * 16 + (lane & 15);
        int off = brow * 128 + (((s * 4 + (lane >> 4)) ^ (brow & 7)) << 4);
        bfr[ni] = *(const half8*)(W_l + off);
      }
      #pragma unroll
      for (int mi = 0; mi < 4; mi++) {
        int arow = mi * 16 + (lane & 15);
        int off = arow * 512 + k0 * 2 + (((s * 4 + (lane >> 4)) ^ (arow & 7)) << 4);
        half8 af = *(const half8*)(T_l + off);
        #pragma unroll
        for (int ni = 0; ni < 4; ni++)
          acc[mi][ni] = __builtin_amdgcn_mfma_f32_16x16x32_f16(af, bfr[ni], acc[mi][ni], 0, 0, 0);
      }
    }
    __builtin_amdgcn_s_barrier();
  }

  // ---- epilogue: X = relu(acc*s + t) (keep v in acc for pooling) ----
  #pragma unroll
  for (int ni = 0; ni < 4; ni++) {
    int col = wn * 64 + ni * 16 + (lane & 15);
    float2 st = ST2[col];
    #pragma unroll
    for (int mi = 0; mi < 4; mi++) {
      int rbase = mi * 16 + (lane >> 4) * 4;
      #pragma unroll
      for (int j = 0; j < 4; j++) {
        float v = fmaxf(fmaf(acc[mi][ni][j], st.x, st.y), 0.f);
        X[(r0 + rbase + j) * CPAD + col] = f2h(v);
        acc[mi][ni][j] = v;
      }
    }
  }

  // ---- fused per-graph pooling of this block's 64 output rows ----
  if (r0 < N_NODES) {
    int rlast = min((int)r0 + 63, N_NODES - 1);
    int gfirst = bv[r0], glast = bv[rlast];
    for (int g = gfirst; g <= glast; ++g) {
      int lo = max(gstart[g], (int)r0) - (int)r0;
      int hi = min(gstart[g + 1], (int)r0 + 64) - (int)r0;
      float ps[4];
      #pragma unroll
      for (int ni = 0; ni < 4; ni++) {
        float a = 0.f;
        #pragma unroll
        for (int mi = 0; mi < 4; mi++) {
          int rbase = mi * 16 + (lane >> 4) * 4;
          #pragma unroll
          for (int j = 0; j < 4; j++) {
            int row = rbase + j;
            a += (row >= lo && row < hi) ? acc[mi][ni][j] : 0.f;
          }
        }
        ps[ni] = a;
      }
      #pragma unroll
      for (int ni = 0; ni < 4; ni++) {
        ps[ni] += __shfl_xor(ps[ni], 16, 64);
        ps[ni] += __shfl_xor(ps[ni], 32, 64);
      }
      if (lane < 16) {
        #pragma unroll
        for (int ni = 0; ni < 4; ni++) {
          int col = wn * 64 + ni * 16 + lane;
          if (col < HID) atomicAdd(&pools_out[g * HID + col], ps[ni]);
        }
      }
    }
  }
}

// head stage 1: one block per (layer i, graph g)
__global__ void head1_kernel(const float* __restrict__ pools, const int* __restrict__ gstart,
                             const float* __restrict__ fcW, const float* __restrict__ fcb,
                             float* __restrict__ partial) {
  __shared__ float red[256];
  int i = blockIdx.x, g = blockIdx.y;
  int t = threadIdx.x;
  int o = t & 15, cg = t >> 4;
  const float* ps = pools + (size_t)(i * N_GRAPHS + g) * HID;
  const float* w = fcW + (size_t)i * HID * NUM_OUT;
  float a = 0.f;
  for (int c = cg; c < HID; c += 16) a = fmaf(ps[c], w[c * NUM_OUT + o], a);
  red[t] = a;
  __syncthreads();
  #pragma unroll
  for (int off = 8; off > 0; off >>= 1) {
    if (cg < off) red[t] += red[t + off * 16];
    __syncthreads();
  }
  if (cg == 0) {
    int cnt = gstart[g + 1] - gstart[g];
    float inv = 1.f / (float)(cnt > 0 ? cnt : 1);
    partial[(i * N_GRAPHS + g) * NUM_OUT + o] = red[t] * inv + fcb[i * NUM_OUT + o];
  }
}

// head stage 2: sum the 6 layer partials
__global__ void head2_kernel(const float* __restrict__ partial, float* __restrict__ out) {
  int t = threadIdx.x;
  if (t >= N_GRAPHS * NUM_OUT) return;
  float acc = 0.f;
  #pragma unroll
  for (int i = 0; i < NLAYERS + 1; ++i) acc += partial[i * N_GRAPHS * NUM_OUT + t];
  out[t] = acc;
}

// ---------------------------------------------------------------------------
extern "C" void kernel_launch(void* const* d_in, const int* in_sizes, int n_in,
                              void* d_out, int out_size, void* d_ws, size_t ws_size,
                              hipStream_t stream) {
  const int*   node_kind    = (const int*)d_in[0];
  const int*   node_content = (const int*)d_in[1];
  const int*   edge_index   = (const int*)d_in[2];
  const int*   edge_type    = (const int*)d_in[3];
  const int*   edge_pos     = (const int*)d_in[4];
  const int*   batch_vec    = (const int*)d_in[5];
  const float* kind_emb     = (const float*)d_in[6];
  const float* inst2vec     = (const float*)d_in[7];
  const float* type_emb     = (const float*)d_in[8];
  const float* etype_emb    = (const float*)d_in[9];
  const float* epos_emb     = (const float*)d_in[10];
  const float* W1   = (const float*)d_in[11];
  const float* b1   = (const float*)d_in[12];
  const float* bn_g = (const float*)d_in[13];
  const float* bn_b = (const float*)d_in[14];
  const float* bn_m = (const float*)d_in[15];
  const float* bn_v = (const float*)d_in[16];
  const float* W2   = (const float*)d_in[17];
  const float* b2   = (const float*)d_in[18];
  const float* fcW  = (const float*)d_in[19];
  const float* fcb  = (const float*)d_in[20];
  float* out = (float*)d_out;

  char* ws = (char*)d_ws;
  ushort_t* x     = (ushort_t*)(ws + 0ull);           // 25,624,576
  ushort_t* y     = (ushort_t*)(ws + 25624576ull);    // 25,624,576
  ushort_t* Wt    = (ushort_t*)(ws + 51249152ull);    // 1,310,720
  float2*   ST    = (float2*)  (ws + 52559872ull);    // 20,480
  uint_t*   ecomb = (uint_t*)  (ws + 52580352ull);    // 31,232
  int*      deg   = (int*)     (ws + 52642816ull);    // 200,000
  int*      offs  = (int*)     (ws + 52842816ull);    // 200,016
  int*      cursor= (int*)     (ws + 53042832ull);    // 200,000
  int*      e_pack= (int*)     (ws + 53242832ull);    // 2,400,064 (padded CSR + sentinel)
  int*      gstart= (int*)     (ws + 55642896ull);    // 260
  float*    pools = (float*)   (ws + 55643156ull);    // 307,200
  int*      bsum  = (int*)     (ws + 55950356ull);    // 784
  int*      bpre  = (int*)     (ws + 55951140ull);    // 784
  float*    partial=(float*)   (ws + 55951924ull);    // 24,576

  const int* srcp = edge_index;
  const int* dstp = edge_index + N_EDGES;

  hipMemsetAsync(deg, 0, N_NODES * sizeof(int), stream);
  hipMemsetAsync(pools, 0, (NLAYERS + 1) * N_GRAPHS * HID * sizeof(float), stream);
  // zero pad rows of y once per launch (agg does not write them)
  hipMemsetAsync(y + (size_t)N_NODES * CPAD, 0, (size_t)(MPAD - N_NODES) * CPAD * 2, stream);

  prep_w<<<(10 * 256 * 256) / 256, 256, 0, stream>>>(W1, W2, Wt);
  prep_st<<<10, 256, 0, stream>>>(b1, bn_g, bn_b, bn_m, bn_v, b2, ST);
  ecomb_kernel<<<61, 128, 0, stream>>>(etype_emb, epos_emb, ecomb);
  embed_pool<<<MPAD / EROWS, 256, 0, stream>>>(node_kind, node_content, kind_emb, inst2vec,
                                               type_emb, batch_vec, x, pools);
  hist_kernel<<<(N_EDGES + 255) / 256, 256, 0, stream>>>(dstp, deg);
  scan1_kernel<<<SCAN_B, 256, 0, stream>>>(deg, bsum);
  scan2_kernel<<<1, 256, 0, stream>>>(bsum, bpre, offs, batch_vec, gstart);
  scan3_kernel<<<SCAN_B, 256, 0, stream>>>(deg, bpre, offs, cursor);
  scatter_kernel<<<(N_EDGES + 255) / 256, 256, 0, stream>>>(srcp, dstp, edge_type, edge_pos,
                                                            cursor, e_pack);
  fill_kernel<<<SCAN_B, 256, 0, stream>>>(cursor, offs, e_pack);

  const int fblocks = MPAD / 64;       // 782
  const int ablocks = N_NODES / 16;    // 3125
  for (int i = 0; i < NLAYERS; ++i) {
    agg_kernel<<<ablocks, 256, 0, stream>>>(x, y, offs, e_pack, ecomb);
    fused_layer<<<fblocks, 256, 0, stream>>>(y, x,
        Wt + (size_t)(2 * i) * 65536, Wt + (size_t)(2 * i + 1) * 65536,
        ST + (size_t)(2 * i) * 256, ST + (size_t)(2 * i + 1) * 256,
        batch_vec, gstart, pools + (size_t)(i + 1) * N_GRAPHS * HID);
  }
  head1_kernel<<<dim3(NLAYERS + 1, N_GRAPHS), 256, 0, stream>>>(pools, gstart, fcW, fcb, partial);
  head2_kernel<<<1, 1024, 0, stream>>>(partial, out);
}

// Round 10
// 446.077 us; speedup vs baseline: 1.1262x; 1.1262x over previous
//
#include <hip/hip_runtime.h>
#include <hip/hip_fp16.h>

#define N_NODES 50000
#define N_EDGES 400000
#define N_GRAPHS 64
#define HID 200
#define NUM_OUT 16
#define NLAYERS 5
#define CPAD 256            // padded channel count (K and N of GEMMs)
#define MPAD 50048          // padded row count (multiple of 64)
#define SCAN_B 196          // ceil(N_NODES/256)
#define EROWS 32            // rows per embed block

typedef unsigned short ushort_t;
typedef unsigned int uint_t;
typedef _Float16 half8 __attribute__((ext_vector_type(8)));
typedef float f32x4 __attribute__((ext_vector_type(4)));

__device__ __forceinline__ ushort_t f2h(float f) {
  return __half_as_ushort(__float2half(f));
}

// packed fp16 helpers
__device__ __forceinline__ uint_t pk_add(uint_t a, uint_t b) {
  uint_t d; asm("v_pk_add_f16 %0, %1, %2" : "=v"(d) : "v"(a), "v"(b)); return d;
}
__device__ __forceinline__ uint_t pk_relu(uint_t a) {
  uint_t d; asm("v_pk_max_f16 %0, %1, 0" : "=v"(d) : "v"(a)); return d;
}

__device__ __forceinline__ void gload_lds16(const void* g, void* l) {
  __builtin_amdgcn_global_load_lds(
      (const __attribute__((address_space(1))) unsigned int*)g,
      (__attribute__((address_space(3))) unsigned int*)l, 16, 0, 0);
}

// ---------------------------------------------------------------------------
// embed + pool0 fused: 32 rows per block, thread = column (fp16 x out).
__global__ __launch_bounds__(256) void embed_pool(
    const int* __restrict__ kind, const int* __restrict__ content,
    const float* __restrict__ kind_emb, const float* __restrict__ inst2vec,
    const float* __restrict__ type_emb, const int* __restrict__ bv,
    ushort_t* __restrict__ x, float* __restrict__ pool0) {
  __shared__ int k_s[EROWS], c_s[EROWS], g_s[EROWS];
  int t = threadIdx.x;
  size_t r0 = (size_t)blockIdx.x * EROWS;
  if (t < EROWS) {
    size_t r = r0 + t;
    int k = 0, cn = 0, g = -1;
    if (r < N_NODES) { k = kind[r]; cn = content[r]; g = bv[r]; }
    k_s[t] = k; c_s[t] = cn; g_s[t] = g;
  }
  __syncthreads();
  int c = t;
  float pacc = 0.f; int gcur = -1;
  #pragma unroll 2
  for (int rr = 0; rr < EROWS; ++rr) {
    size_t r = r0 + rr;
    if (r < N_NODES) {
      float f = 0.f;
      if (c < HID) {
        int k = k_s[rr];
        f = kind_emb[k * HID + c] +
            ((k == 0) ? inst2vec[(size_t)c_s[rr] * HID + c] : type_emb[c]);
      }
      x[r * CPAD + c] = f2h(f);
      int g = g_s[rr];
      if (g != gcur) {
        if (gcur >= 0 && c < HID) atomicAdd(&pool0[gcur * HID + c], pacc);
        pacc = 0.f; gcur = g;
      }
      pacc += f;
    } else {
      x[r * CPAD + c] = 0;
    }
  }
  if (gcur >= 0 && c < HID) atomicAdd(&pool0[gcur * HID + c], pacc);
}

// edge-embedding table, packed fp16: ecomb[61][128] uints (=256 half channels).
// Row 60 = -65504 sentinel (dummy edges; relu clamps to 0).
__global__ void ecomb_kernel(const float* __restrict__ etype_emb, const float* __restrict__ epos_emb,
                             uint_t* __restrict__ ecomb) {
  int code = blockIdx.x; int cp = threadIdx.x;   // cp in [0,128)
  if (cp >= 128) return;
  uint_t v;
  if (code == 60) {
    v = 0xFBFFFBFFu;   // half -65504 in both halves
  } else {
    int c0 = cp * 2, c1 = cp * 2 + 1;
    float f0 = (c0 < HID) ? etype_emb[(code / 20) * HID + c0] + epos_emb[(code % 20) * HID + c0] : 0.f;
    float f1 = (c1 < HID) ? etype_emb[(code / 20) * HID + c1] + epos_emb[(code % 20) * HID + c1] : 0.f;
    v = (uint_t)f2h(f0) | ((uint_t)f2h(f1) << 16);
  }
  ecomb[code * 128 + cp] = v;
}

// weights: fp16, transposed, padded.  Wt[g][n][k], g=2i -> W1[i], g=2i+1 -> W2[i]
__global__ void prep_w(const float* __restrict__ W1, const float* __restrict__ W2,
                       ushort_t* __restrict__ Wt) {
  int idx = blockIdx.x * 256 + threadIdx.x;   // 10*256*256 total
  int g = idx >> 16; int rem = idx & 65535; int n = rem >> 8; int k = rem & 255;
  float v = 0.f;
  if (n < HID && k < HID) {
    int i = g >> 1;
    v = (g & 1) ? W2[(size_t)i * HID * HID + (size_t)k * HID + n]
                : W1[(size_t)i * HID * HID + (size_t)k * HID + n];
  }
  Wt[idx] = f2h(v);
}

// epilogue tables: out = relu(acc*s + t); pad channels s=t=0 (keeps pads zero)
__global__ void prep_st(const float* __restrict__ b1, const float* __restrict__ bn_g,
                        const float* __restrict__ bn_b, const float* __restrict__ bn_m,
                        const float* __restrict__ bn_v, const float* __restrict__ b2,
                        float2* __restrict__ ST) {
  int idx = blockIdx.x * 256 + threadIdx.x;   // 10*256
  int g = idx >> 8, c = idx & 255;
  float s = 0.f, t = 0.f;
  if (c < HID) {
    int i = g >> 1;
    if (g & 1) { s = 1.f; t = b2[i * HID + c]; }
    else {
      float sc = bn_g[i * HID + c] * rsqrtf(bn_v[i * HID + c] + 1e-5f);
      s = sc; t = (b1[i * HID + c] - bn_m[i * HID + c]) * sc + bn_b[i * HID + c];
    }
  }
  ST[idx] = make_float2(s, t);
}

// CSR build (padded degrees: multiple of 4)
__global__ void hist_kernel(const int* __restrict__ dst, int* __restrict__ deg) {
  int e = blockIdx.x * 256 + threadIdx.x;
  if (e < N_EDGES) atomicAdd(&deg[dst[e]], 1);
}

__global__ void scan1_kernel(const int* __restrict__ deg, int* __restrict__ bsum) {
  __shared__ int red[256];
  int b = blockIdx.x, t = threadIdx.x;
  int i = b * 256 + t;
  red[t] = (i < N_NODES) ? ((deg[i] + 3) & ~3) : 0;
  __syncthreads();
  for (int off = 128; off > 0; off >>= 1) {
    if (t < off) red[t] += red[t + off];
    __syncthreads();
  }
  if (t == 0) bsum[b] = red[0];
}

__global__ void scan2_kernel(const int* __restrict__ bsum, int* __restrict__ bpre,
                             int* __restrict__ offs, const int* __restrict__ bv,
                             int* __restrict__ gstart) {
  __shared__ int buf[256];
  int t = threadIdx.x;
  if (t <= N_GRAPHS) {
    if (t == N_GRAPHS) gstart[N_GRAPHS] = N_NODES;
    else {
      int lo = 0, hi = N_NODES;
      while (lo < hi) { int mid = (lo + hi) >> 1; if (bv[mid] < t) lo = mid + 1; else hi = mid; }
      gstart[t] = lo;
    }
  }
  int v = (t < SCAN_B) ? bsum[t] : 0;
  buf[t] = v;
  __syncthreads();
  for (int off = 1; off < 256; off <<= 1) {
    int tv = (t >= off) ? buf[t - off] : 0;
    __syncthreads();
    buf[t] += tv;
    __syncthreads();
  }
  if (t < SCAN_B) bpre[t] = buf[t] - v;
  if (t == 255) offs[N_NODES] = buf[255];
}

__global__ void scan3_kernel(const int* __restrict__ deg, const int* __restrict__ bpre,
                             int* __restrict__ offs, int* __restrict__ cursor) {
  __shared__ int buf[256];
  int b = blockIdx.x, t = threadIdx.x;
  int i = b * 256 + t;
  int v = (i < N_NODES) ? ((deg[i] + 3) & ~3) : 0;
  buf[t] = v;
  __syncthreads();
  for (int off = 1; off < 256; off <<= 1) {
    int tv = (t >= off) ? buf[t - off] : 0;
    __syncthreads();
    buf[t] += tv;
    __syncthreads();
  }
  if (i < N_NODES) {
    int e = bpre[b] + buf[t] - v;
    offs[i] = e; cursor[i] = e;
  }
}

// scatter real edges: pack (src,code) into one int
__global__ void scatter_kernel(const int* __restrict__ src, const int* __restrict__ dst,
                               const int* __restrict__ etype, const int* __restrict__ epos,
                               int* __restrict__ cursor, int* __restrict__ e_pack) {
  int e = blockIdx.x * 256 + threadIdx.x;
  if (e >= N_EDGES) return;
  int d = dst[e];
  int slot = atomicAdd(&cursor[d], 1);
  int p = epos[e]; if (p > 19) p = 19;
  e_pack[slot] = (src[e] << 6) | (etype[e] * 20 + p);
}

// fill padding slots with dummy edges: src = node 0 (L1-hot row) + sentinel
// code 60 (-65504 -> relu 0 regardless of x[0]).
__global__ void fill_kernel(const int* __restrict__ cursor, const int* __restrict__ offs,
                            int* __restrict__ e_pack) {
  int n = blockIdx.x * 256 + threadIdx.x;
  if (n >= N_NODES) return;
  int e = offs[n + 1];
  for (int j = cursor[n]; j < e; ++j) e_pack[j] = 60;   // (0<<6)|60
}

// GINE aggregation (fp16 packed math): one wave per 2 nodes, two interleaved
// edge streams (8 x-gathers in flight) + next-chunk e_pack prefetch to take
// the index-load latency off the critical path.  Lanes 0..49 = 200 channels.
__global__ __launch_bounds__(256) void agg_kernel(
    const ushort_t* __restrict__ x, ushort_t* __restrict__ y,
    const int* __restrict__ offs, const int* __restrict__ e_pack,
    const uint_t* __restrict__ ecomb) {
  int wid = threadIdx.x >> 6, lane = threadIdx.x & 63;
  int n0 = (blockIdx.x * 4 + wid) * 2;
  if (n0 >= N_NODES) return;
  int n1 = n0 + 1;   // N_NODES even -> always valid
  const uint2* xv = (const uint2*)x;     // 4 fp16 ch per lane
  const uint2* ecv = (const uint2*)ecomb;
  uint2* yv = (uint2*)y;
  if (lane >= 50) {
    yv[(size_t)n0 * 64 + lane] = make_uint2(0u, 0u);
    yv[(size_t)n1 * 64 + lane] = make_uint2(0u, 0u);
    return;
  }
  int j0 = offs[n0], e0 = offs[n0 + 1];
  int j1 = offs[n1], e1 = offs[n1 + 1];
  uint_t a0l = 0u, a0h = 0u, a1l = 0u, a1h = 0u;
  const int4* ep4 = (const int4*)e_pack;

  // main loop: both streams active, software-pipelined e_pack prefetch
  bool has = (j0 < e0) && (j1 < e1);
  int4 p0, p1;
  if (has) { p0 = ep4[j0 >> 2]; p1 = ep4[j1 >> 2]; }
  while (has) {
    int nj0 = j0 + 4, nj1 = j1 + 4;
    bool nhas = (nj0 < e0) && (nj1 < e1);
    int4 q0, q1;
    if (nhas) { q0 = ep4[nj0 >> 2]; q1 = ep4[nj1 >> 2]; }   // prefetch next chunk
    uint2 xa0 = xv[(size_t)(p0.x >> 6) * 64 + lane];
    uint2 xa1 = xv[(size_t)(p0.y >> 6) * 64 + lane];
    uint2 xa2 = xv[(size_t)(p0.z >> 6) * 64 + lane];
    uint2 xa3 = xv[(size_t)(p0.w >> 6) * 64 + lane];
    uint2 xb0 = xv[(size_t)(p1.x >> 6) * 64 + lane];
    uint2 xb1 = xv[(size_t)(p1.y >> 6) * 64 + lane];
    uint2 xb2 = xv[(size_t)(p1.z >> 6) * 64 + lane];
    uint2 xb3 = xv[(size_t)(p1.w >> 6) * 64 + lane];
    uint2 ea0 = ecv[(size_t)(p0.x & 63) * 64 + lane];
    uint2 ea1 = ecv[(size_t)(p0.y & 63) * 64 + lane];
    uint2 ea2 = ecv[(size_t)(p0.z & 63) * 64 + lane];
    uint2 ea3 = ecv[(size_t)(p0.w & 63) * 64 + lane];
    uint2 eb0 = ecv[(size_t)(p1.x & 63) * 64 + lane];
    uint2 eb1 = ecv[(size_t)(p1.y & 63) * 64 + lane];
    uint2 eb2 = ecv[(size_t)(p1.z & 63) * 64 + lane];
    uint2 eb3 = ecv[(size_t)(p1.w & 63) * 64 + lane];
    a0l = pk_add(a0l, pk_relu(pk_add(xa0.x, ea0.x)));
    a0h = pk_add(a0h, pk_relu(pk_add(xa0.y, ea0.y)));
    a0l = pk_add(a0l, pk_relu(pk_add(xa1.x, ea1.x)));
    a0h = pk_add(a0h, pk_relu(pk_add(xa1.y, ea1.y)));
    a0l = pk_add(a0l, pk_relu(pk_add(xa2.x, ea2.x)));
    a0h = pk_add(a0h, pk_relu(pk_add(xa2.y, ea2.y)));
    a0l = pk_add(a0l, pk_relu(pk_add(xa3.x, ea3.x)));
    a0h = pk_add(a0h, pk_relu(pk_add(xa3.y, ea3.y)));
    a1l = pk_add(a1l, pk_relu(pk_add(xb0.x, eb0.x)));
    a1h = pk_add(a1h, pk_relu(pk_add(xb0.y, eb0.y)));
    a1l = pk_add(a1l, pk_relu(pk_add(xb1.x, eb1.x)));
    a1h = pk_add(a1h, pk_relu(pk_add(xb1.y, eb1.y)));
    a1l = pk_add(a1l, pk_relu(pk_add(xb2.x, eb2.x)));
    a1h = pk_add(a1h, pk_relu(pk_add(xb2.y, eb2.y)));
    a1l = pk_add(a1l, pk_relu(pk_add(xb3.x, eb3.x)));
    a1h = pk_add(a1h, pk_relu(pk_add(xb3.y, eb3.y)));
    p0 = q0; p1 = q1; j0 = nj0; j1 = nj1; has = nhas;
  }
  // stream-0 tail
  for (; j0 < e0; j0 += 4) {
    int4 p = ep4[j0 >> 2];
    uint2 xa0 = xv[(size_t)(p.x >> 6) * 64 + lane];
    uint2 xa1 = xv[(size_t)(p.y >> 6) * 64 + lane];
    uint2 xa2 = xv[(size_t)(p.z >> 6) * 64 + lane];
    uint2 xa3 = xv[(size_t)(p.w >> 6) * 64 + lane];
    uint2 ea0 = ecv[(size_t)(p.x & 63) * 64 + lane];
    uint2 ea1 = ecv[(size_t)(p.y & 63) * 64 + lane];
    uint2 ea2 = ecv[(size_t)(p.z & 63) * 64 + lane];
    uint2 ea3 = ecv[(size_t)(p.w & 63) * 64 + lane];
    a0l = pk_add(a0l, pk_relu(pk_add(xa0.x, ea0.x)));
    a0h = pk_add(a0h, pk_relu(pk_add(xa0.y, ea0.y)));
    a0l = pk_add(a0l, pk_relu(pk_add(xa1.x, ea1.x)));
    a0h = pk_add(a0h, pk_relu(pk_add(xa1.y, ea1.y)));
    a0l = pk_add(a0l, pk_relu(pk_add(xa2.x, ea2.x)));
    a0h = pk_add(a0h, pk_relu(pk_add(xa2.y, ea2.y)));
    a0l = pk_add(a0l, pk_relu(pk_add(xa3.x, ea3.x)));
    a0h = pk_add(a0h, pk_relu(pk_add(xa3.y, ea3.y)));
  }
  // stream-1 tail
  for (; j1 < e1; j1 += 4) {
    int4 p = ep4[j1 >> 2];
    uint2 xb0 = xv[(size_t)(p.x >> 6) * 64 + lane];
    uint2 xb1 = xv[(size_t)(p.y >> 6) * 64 + lane];
    uint2 xb2 = xv[(size_t)(p.z >> 6) * 64 + lane];
    uint2 xb3 = xv[(size_t)(p.w >> 6) * 64 + lane];
    uint2 eb0 = ecv[(size_t)(p.x & 63) * 64 + lane];
    uint2 eb1 = ecv[(size_t)(p.y & 63) * 64 + lane];
    uint2 eb2 = ecv[(size_t)(p.z & 63) * 64 + lane];
    uint2 eb3 = ecv[(size_t)(p.w & 63) * 64 + lane];
    a1l = pk_add(a1l, pk_relu(pk_add(xb0.x, eb0.x)));
    a1h = pk_add(a1h, pk_relu(pk_add(xb0.y, eb0.y)));
    a1l = pk_add(a1l, pk_relu(pk_add(xb1.x, eb1.x)));
    a1h = pk_add(a1h, pk_relu(pk_add(xb1.y, eb1.y)));
    a1l = pk_add(a1l, pk_relu(pk_add(xb2.x, eb2.x)));
    a1h = pk_add(a1h, pk_relu(pk_add(xb2.y, eb2.y)));
    a1l = pk_add(a1l, pk_relu(pk_add(xb3.x, eb3.x)));
    a1h = pk_add(a1h, pk_relu(pk_add(xb3.y, eb3.y)));
  }
  uint2 xn0 = xv[(size_t)n0 * 64 + lane];
  uint2 xn1 = xv[(size_t)n1 * 64 + lane];
  uint2 o0, o1;
  o0.x = pk_add(xn0.x, a0l); o0.y = pk_add(xn0.y, a0h);
  o1.x = pk_add(xn1.x, a1l); o1.y = pk_add(xn1.y, a1h);
  yv[(size_t)n0 * 64 + lane] = o0;
  yv[(size_t)n1 * 64 + lane] = o1;
}

// ---------------------------------------------------------------------------
// Fused layer (fp16): X = relu(relu(BN(Y@W1)) @ W2 + b2) + per-graph pooling.
__global__ __launch_bounds__(256, 2) void fused_layer(
    const ushort_t* __restrict__ Y, ushort_t* __restrict__ X,
    const ushort_t* __restrict__ W1t, const ushort_t* __restrict__ W2t,
    const float2* __restrict__ ST1, const float2* __restrict__ ST2,
    const int* __restrict__ bv, const int* __restrict__ gstart,
    float* __restrict__ pools_out) {
  __shared__ char lds[80 * 1024];
  char* A_l0 = lds;             //  8KB: 64 rows x 128B (A k-tile, buf 0)
  char* A_l1 = lds + 8192;      //  8KB: buf 1
  char* W_l  = lds + 16384;     // 32KB: 256 rows x 128B (W1/W2 k-tile)
  char* T_l  = lds + 49152;     // 32KB: 64 rows x 512B (intermediate, swizzled)
  const int tid = threadIdx.x;
  const int lane = tid & 63, wn = tid >> 6;
  const size_t r0 = (size_t)blockIdx.x * 64;
  const char* Ab = (const char*)Y;
  const char* W1c = (const char*)W1t;
  const char* W2c = (const char*)W2t;

  f32x4 acc[4][4];
  #pragma unroll
  for (int mi = 0; mi < 4; mi++)
    #pragma unroll
    for (int ni = 0; ni < 4; ni++) acc[mi][ni] = (f32x4){0.f, 0.f, 0.f, 0.f};

  // ---- phase A: acc = Y_tile @ W1, pipelined ----
  {
    #pragma unroll
    for (int c = 0; c < 2; c++) {
      int d = tid * 16 + c * 4096;
      int rowd = d >> 7, slot = (d >> 4) & 7, lslot = slot ^ (rowd & 7);
      gload_lds16(Ab + (r0 + rowd) * 512 + 0 + lslot * 16, A_l0 + d);
    }
    #pragma unroll
    for (int t = 0; t < 4; ++t) {
      const int k0 = t * 64;
      #pragma unroll
      for (int c = 0; c < 8; c++) {
        int d = tid * 16 + c * 4096;
        int rowd = d >> 7, slot = (d >> 4) & 7, lslot = slot ^ (rowd & 7);
        gload_lds16(W1c + (size_t)rowd * 512 + k0 * 2 + lslot * 16, W_l + d);
      }
      if (t < 3) {
        char* nbuf = (t & 1) ? A_l0 : A_l1;
        #pragma unroll
        for (int c = 0; c < 2; c++) {
          int d = tid * 16 + c * 4096;
          int rowd = d >> 7, slot = (d >> 4) & 7, lslot = slot ^ (rowd & 7);
          gload_lds16(Ab + (r0 + rowd) * 512 + (k0 + 64) * 2 + lslot * 16, nbuf + d);
        }
        asm volatile("s_waitcnt vmcnt(2)" ::: "memory");
      } else {
        asm volatile("s_waitcnt vmcnt(0)" ::: "memory");
      }
      __builtin_amdgcn_sched_barrier(0);
      __builtin_amdgcn_s_barrier();
      const char* Abuf = (t & 1) ? A_l1 : A_l0;
      #pragma unroll
      for (int s = 0; s < 2; s++) {
        half8 bfr[4];
        #pragma unroll
        for (int ni = 0; ni < 4; ni++) {
          int brow = wn * 64 + ni * 16 + (lane & 15);
          int off = brow * 128 + (((s * 4 + (lane >> 4)) ^ (brow & 7)) << 4);
          bfr[ni] = *(const half8*)(W_l + off);
        }
        #pragma unroll
        for (int mi = 0; mi < 4; mi++) {
          int arow = mi * 16 + (lane & 15);
          int off = arow * 128 + (((s * 4 + (lane >> 4)) ^ (arow & 7)) << 4);
          half8 af = *(const half8*)(Abuf + off);
          #pragma unroll
          for (int ni = 0; ni < 4; ni++)
            acc[mi][ni] = __builtin_amdgcn_mfma_f32_16x16x32_f16(af, bfr[ni], acc[mi][ni], 0, 0, 0);
        }
      }
      __builtin_amdgcn_s_barrier();
    }
  }

  // ---- T = relu(BN(acc)) -> LDS (fp16, swizzled rows of 512B) ----
  #pragma unroll
  for (int ni = 0; ni < 4; ni++) {
    int col = wn * 64 + ni * 16 + (lane & 15);
    float2 st = ST1[col];
    #pragma unroll
    for (int mi = 0; mi < 4; mi++) {
      int rbase = mi * 16 + (lane >> 4) * 4;
      #pragma unroll
      for (int j = 0; j < 4; j++) {
        int row = rbase + j;
        float v = fmaxf(fmaf(acc[mi][ni][j], st.x, st.y), 0.f);
        int boff = row * 512 + ((((col >> 3) ^ (row & 7)) << 4) | ((col & 7) * 2));
        *(ushort_t*)(T_l + boff) = f2h(v);
      }
    }
  }
  #pragma unroll
  for (int mi = 0; mi < 4; mi++)
    #pragma unroll
    for (int ni = 0; ni < 4; ni++) acc[mi][ni] = (f32x4){0.f, 0.f, 0.f, 0.f};
  __syncthreads();

  // ---- phase B: acc = T @ W2 (W2 L2-hot; simple stage/drain per k-tile) ----
  #pragma unroll
  for (int t = 0; t < 4; ++t) {
    const int k0 = t * 64;
    #pragma unroll
    for (int c = 0; c < 8; c++) {
      int d = tid * 16 + c * 4096;
      int rowd = d >> 7, slot = (d >> 4) & 7, lslot = slot ^ (rowd & 7);
      gload_lds16(W2c + (size_t)rowd * 512 + k0 * 2 + lslot * 16, W_l + d);
    }
    asm volatile("s_waitcnt vmcnt(0)" ::: "memory");
    __builtin_amdgcn_sched_barrier(0);
    __builtin_amdgcn_s_barrier();
    #pragma unroll
    for (int s = 0; s < 2; s++) {
      half8 bfr[4];
      #pragma unroll
      for (int ni = 0; ni < 4; ni++) {
        int brow = wn * 64 + ni * 16 + (lane & 15);
        int off = brow * 128 + (((s * 4 + (lane >> 4)) ^ (brow & 7)) << 4);
        bfr[ni] = *(const half8*)(W_l + off);
      }
      #pragma unroll
      for (int mi = 0; mi < 4; mi++) {
        int arow = mi * 16 + (lane & 15);
        int off = arow * 512 + k0 * 2 + (((s * 4 + (lane >> 4)) ^ (arow & 7)) << 4);
        half8 af = *(const half8*)(T_l + off);
        #pragma unroll
        for (int ni = 0; ni < 4; ni++)
          acc[mi][ni] = __builtin_amdgcn_mfma_f32_16x16x32_f16(af, bfr[ni], acc[mi][ni], 0, 0, 0);
      }
    }
    __builtin_amdgcn_s_barrier();
  }

  // ---- epilogue: X = relu(acc*s + t) (keep v in acc for pooling) ----
  #pragma unroll
  for (int ni = 0; ni < 4; ni++) {
    int col = wn * 64 + ni * 16 + (lane & 15);
    float2 st = ST2[col];
    #pragma unroll
    for (int mi = 0; mi < 4; mi++) {
      int rbase = mi * 16 + (lane >> 4) * 4;
      #pragma unroll
      for (int j = 0; j < 4; j++) {
        float v = fmaxf(fmaf(acc[mi][ni][j], st.x, st.y), 0.f);
        X[(r0 + rbase + j) * CPAD + col] = f2h(v);
        acc[mi][ni][j] = v;
      }
    }
  }

  // ---- fused per-graph pooling of this block's 64 output rows ----
  if (r0 < N_NODES) {
    int rlast = min((int)r0 + 63, N_NODES - 1);
    int gfirst = bv[r0], glast = bv[rlast];
    for (int g = gfirst; g <= glast; ++g) {
      int lo = max(gstart[g], (int)r0) - (int)r0;
      int hi = min(gstart[g + 1], (int)r0 + 64) - (int)r0;
      float ps[4];
      #pragma unroll
      for (int ni = 0; ni < 4; ni++) {
        float a = 0.f;
        #pragma unroll
        for (int mi = 0; mi < 4; mi++) {
          int rbase = mi * 16 + (lane >> 4) * 4;
          #pragma unroll
          for (int j = 0; j < 4; j++) {
            int row = rbase + j;
            a += (row >= lo && row < hi) ? acc[mi][ni][j] : 0.f;
          }
        }
        ps[ni] = a;
      }
      #pragma unroll
      for (int ni = 0; ni < 4; ni++) {
        ps[ni] += __shfl_xor(ps[ni], 16, 64);
        ps[ni] += __shfl_xor(ps[ni], 32, 64);
      }
      if (lane < 16) {
        #pragma unroll
        for (int ni = 0; ni < 4; ni++) {
          int col = wn * 64 + ni * 16 + lane;
          if (col < HID) atomicAdd(&pools_out[g * HID + col], ps[ni]);
        }
      }
    }
  }
}

// head stage 1: one block per (layer i, graph g)
__global__ void head1_kernel(const float* __restrict__ pools, const int* __restrict__ gstart,
                             const float* __restrict__ fcW, const float* __restrict__ fcb,
                             float* __restrict__ partial) {
  __shared__ float red[256];
  int i = blockIdx.x, g = blockIdx.y;
  int t = threadIdx.x;
  int o = t & 15, cg = t >> 4;
  const float* ps = pools + (size_t)(i * N_GRAPHS + g) * HID;
  const float* w = fcW + (size_t)i * HID * NUM_OUT;
  float a = 0.f;
  for (int c = cg; c < HID; c += 16) a = fmaf(ps[c], w[c * NUM_OUT + o], a);
  red[t] = a;
  __syncthreads();
  #pragma unroll
  for (int off = 8; off > 0; off >>= 1) {
    if (cg < off) red[t] += red[t + off * 16];
    __syncthreads();
  }
  if (cg == 0) {
    int cnt = gstart[g + 1] - gstart[g];
    float inv = 1.f / (float)(cnt > 0 ? cnt : 1);
    partial[(i * N_GRAPHS + g) * NUM_OUT + o] = red[t] * inv + fcb[i * NUM_OUT + o];
  }
}

// head stage 2: sum the 6 layer partials
__global__ void head2_kernel(const float* __restrict__ partial, float* __restrict__ out) {
  int t = threadIdx.x;
  if (t >= N_GRAPHS * NUM_OUT) return;
  float acc = 0.f;
  #pragma unroll
  for (int i = 0; i < NLAYERS + 1; ++i) acc += partial[i * N_GRAPHS * NUM_OUT + t];
  out[t] = acc;
}

// ---------------------------------------------------------------------------
extern "C" void kernel_launch(void* const* d_in, const int* in_sizes, int n_in,
                              void* d_out, int out_size, void* d_ws, size_t ws_size,
                              hipStream_t stream) {
  const int*   node_kind    = (const int*)d_in[0];
  const int*   node_content = (const int*)d_in[1];
  const int*   edge_index   = (const int*)d_in[2];
  const int*   edge_type    = (const int*)d_in[3];
  const int*   edge_pos     = (const int*)d_in[4];
  const int*   batch_vec    = (const int*)d_in[5];
  const float* kind_emb     = (const float*)d_in[6];
  const float* inst2vec     = (const float*)d_in[7];
  const float* type_emb     = (const float*)d_in[8];
  const float* etype_emb    = (const float*)d_in[9];
  const float* epos_emb     = (const float*)d_in[10];
  const float* W1   = (const float*)d_in[11];
  const float* b1   = (const float*)d_in[12];
  const float* bn_g = (const float*)d_in[13];
  const float* bn_b = (const float*)d_in[14];
  const float* bn_m = (const float*)d_in[15];
  const float* bn_v = (const float*)d_in[16];
  const float* W2   = (const float*)d_in[17];
  const float* b2   = (const float*)d_in[18];
  const float* fcW  = (const float*)d_in[19];
  const float* fcb  = (const float*)d_in[20];
  float* out = (float*)d_out;

  char* ws = (char*)d_ws;
  ushort_t* x     = (ushort_t*)(ws + 0ull);           // 25,624,576
  ushort_t* y     = (ushort_t*)(ws + 25624576ull);    // 25,624,576
  ushort_t* Wt    = (ushort_t*)(ws + 51249152ull);    // 1,310,720
  float2*   ST    = (float2*)  (ws + 52559872ull);    // 20,480
  uint_t*   ecomb = (uint_t*)  (ws + 52580352ull);    // 31,232
  int*      deg   = (int*)     (ws + 52642816ull);    // 200,000
  int*      offs  = (int*)     (ws + 52842816ull);    // 200,016
  int*      cursor= (int*)     (ws + 53042832ull);    // 200,000
  int*      e_pack= (int*)     (ws + 53242832ull);    // 2,400,064 (padded CSR)
  int*      gstart= (int*)     (ws + 55642896ull);    // 260
  float*    pools = (float*)   (ws + 55643156ull);    // 307,200
  int*      bsum  = (int*)     (ws + 55950356ull);    // 784
  int*      bpre  = (int*)     (ws + 55951140ull);    // 784
  float*    partial=(float*)   (ws + 55951924ull);    // 24,576

  const int* srcp = edge_index;
  const int* dstp = edge_index + N_EDGES;

  hipMemsetAsync(deg, 0, N_NODES * sizeof(int), stream);
  hipMemsetAsync(pools, 0, (NLAYERS + 1) * N_GRAPHS * HID * sizeof(float), stream);
  // zero pad rows of y once per launch (agg does not write them)
  hipMemsetAsync(y + (size_t)N_NODES * CPAD, 0, (size_t)(MPAD - N_NODES) * CPAD * 2, stream);

  prep_w<<<(10 * 256 * 256) / 256, 256, 0, stream>>>(W1, W2, Wt);
  prep_st<<<10, 256, 0, stream>>>(b1, bn_g, bn_b, bn_m, bn_v, b2, ST);
  ecomb_kernel<<<61, 128, 0, stream>>>(etype_emb, epos_emb, ecomb);
  embed_pool<<<MPAD / EROWS, 256, 0, stream>>>(node_kind, node_content, kind_emb, inst2vec,
                                               type_emb, batch_vec, x, pools);
  hist_kernel<<<(N_EDGES + 255) / 256, 256, 0, stream>>>(dstp, deg);
  scan1_kernel<<<SCAN_B, 256, 0, stream>>>(deg, bsum);
  scan2_kernel<<<1, 256, 0, stream>>>(bsum, bpre, offs, batch_vec, gstart);
  scan3_kernel<<<SCAN_B, 256, 0, stream>>>(deg, bpre, offs, cursor);
  scatter_kernel<<<(N_EDGES + 255) / 256, 256, 0, stream>>>(srcp, dstp, edge_type, edge_pos,
                                                            cursor, e_pack);
  fill_kernel<<<SCAN_B, 256, 0, stream>>>(cursor, offs, e_pack);

  const int fblocks = MPAD / 64;               // 782
  const int ablocks = (N_NODES / 2 + 3) / 4;   // 6250
  for (int i = 0; i < NLAYERS; ++i) {
    agg_kernel<<<ablocks, 256, 0, stream>>>(x, y, offs, e_pack, ecomb);
    fused_layer<<<fblocks, 256, 0, stream>>>(y, x,
        Wt + (size_t)(2 * i) * 65536, Wt + (size_t)(2 * i + 1) * 65536,
        ST + (size_t)(2 * i) * 256, ST + (size_t)(2 * i + 1) * 256,
        batch_vec, gstart, pools + (size_t)(i + 1) * N_GRAPHS * HID);
  }
  head1_kernel<<<dim3(NLAYERS + 1, N_GRAPHS), 256, 0, stream>>>(pools, gstart, fcW, fcb, partial);
  head2_kernel<<<1, 1024, 0, stream>>>(partial, out);
}